// Round 1
// baseline (91.879 us; speedup 1.0000x reference)
//
#include <hip/hip_runtime.h>
#include <hip/hip_bf16.h>

// FerroelectricBasis: out[b,o] = sum_{i,n} [ branch(b,i)*Ps*(2*sig(k*(x-Ec))-1)
//                                          + (1-branch)*Ps*(2*sig(k*(x+Ec))-1) + bias ] * coef
// branch(b,i) = (x[b,i] - x[b-1,i] > 0)   (row 0: prev = 0)
//
// Folded form:  out[b,o] = sum_{i,n} A * sigmoid_eval + C0[o]
//   A  = 2*Ps*coef
//   C0[o] = sum_{i,n} (bias - Ps)*coef
//   sigmoid_eval = 1 / (1 + exp2(kk*x + (branch ? +E : -E)))
//   kk = -log2(e)*k,  E = log2(e)*k*Ec
//
// B=1024, I=64, O=64, N=16.  Transcendental-bound (~67M exp+rcp).

#define LOG2E 1.44269504088896340736f
#define B_DIM 1024
#define I_DIM 64
#define O_DIM 64
#define N_DIM 16
#define ION (I_DIM * O_DIM * N_DIM)   // 65536

__device__ __forceinline__ float ex2(float x) {
#if __has_builtin(__builtin_amdgcn_exp2f)
  return __builtin_amdgcn_exp2f(x);
#else
  return exp2f(x);
#endif
}

__global__ void zero_c0(float* C0) { C0[threadIdx.x] = 0.0f; }

// Transform params: P4[idx] = {kk, E, A, 0}; C0[o] += (bias - Ps)*coef
__global__ __launch_bounds__(256) void transform_k(
    const float* __restrict__ k, const float* __restrict__ Ec,
    const float* __restrict__ Ps, const float* __restrict__ bias,
    const float* __restrict__ coef, float4* __restrict__ P4,
    float* __restrict__ C0) {
  int idx = blockIdx.x * 256 + threadIdx.x;  // 0..65535 ; idx = i*1024 + o*16 + n
  float kv = k[idx], ev = Ec[idx], pv = Ps[idx], bv = bias[idx], cv = coef[idx];
  float kk = -LOG2E * kv;
  float E  =  LOG2E * kv * ev;
  float A  =  2.0f * pv * cv;
  P4[idx] = make_float4(kk, E, A, 0.0f);
  float cpart = (bv - pv) * cv;
  // 16 consecutive lanes share the same (i,o) -> same o; shuffle-reduce then one atomic
  #pragma unroll
  for (int off = 1; off < 16; off <<= 1)
    cpart += __shfl_xor(cpart, off, 64);
  if ((threadIdx.x & 15) == 0)
    atomicAdd(&C0[(idx >> 4) & (O_DIM - 1)], cpart);
}

__global__ __launch_bounds__(256) void out_init(const float* __restrict__ C0,
                                                float* __restrict__ out) {
  int gid = blockIdx.x * 256 + threadIdx.x;  // 65536 outputs
  out[gid] = C0[gid & (O_DIM - 1)];
}

// Main: grid = 16 i-chunks x 32 b-chunks = 512 blocks, 256 threads.
// thread t: o = t>>2, bs = t&3 -> owns rows [bc*32 + bs*8, +8), i in [ic*4, +4), all n.
// Params held in registers, amortized over 8 b-rows. Partial sums -> atomicAdd.
__global__ __launch_bounds__(256) void ferro_main(
    const float* __restrict__ x, const float4* __restrict__ P4,
    float* __restrict__ out) {
  int t  = threadIdx.x;
  int o  = t >> 2;                 // 0..63
  int bs = t & 3;                  // 0..3
  int ic = blockIdx.x & 15;        // i-chunk (same-ic blocks land on same XCD)
  int bc = blockIdx.x >> 4;        // 0..31
  int r0 = bc * 32 + bs * 8;       // first of 8 rows

  float acc[8];
  #pragma unroll
  for (int j = 0; j < 8; ++j) acc[j] = 0.0f;

  for (int ii = 0; ii < 4; ++ii) {
    int i = ic * 4 + ii;
    float xv[9];
    xv[0] = (r0 == 0) ? 0.0f : x[(r0 - 1) * I_DIM + i];
    #pragma unroll
    for (int j = 0; j < 8; ++j) xv[j + 1] = x[(r0 + j) * I_DIM + i];
    bool br[8];
    #pragma unroll
    for (int j = 0; j < 8; ++j) br[j] = xv[j + 1] > xv[j];

    const float4* p = &P4[(i * O_DIM + o) * N_DIM];
    #pragma unroll
    for (int n = 0; n < N_DIM; ++n) {
      float4 pv = p[n];
      float kk = pv.x, E = pv.y, A = pv.z;
      #pragma unroll
      for (int j = 0; j < 8; ++j) {
        float e = br[j] ? E : -E;
        float z = fmaf(kk, xv[j + 1], e);
        float tt = ex2(z);
        float r  = __builtin_amdgcn_rcpf(1.0f + tt);
        acc[j] = fmaf(A, r, acc[j]);
      }
    }
  }

  #pragma unroll
  for (int j = 0; j < 8; ++j)
    atomicAdd(&out[(r0 + j) * O_DIM + o], acc[j]);
}

extern "C" void kernel_launch(void* const* d_in, const int* in_sizes, int n_in,
                              void* d_out, int out_size, void* d_ws, size_t ws_size,
                              hipStream_t stream) {
  const float* x    = (const float*)d_in[0];
  const float* k    = (const float*)d_in[1];
  const float* Ec   = (const float*)d_in[2];
  const float* Ps   = (const float*)d_in[3];
  const float* bias = (const float*)d_in[4];
  const float* coef = (const float*)d_in[5];
  float* out = (float*)d_out;

  float4* P4 = (float4*)d_ws;
  float*  C0 = (float*)((char*)d_ws + (size_t)ION * sizeof(float4));

  hipLaunchKernelGGL(zero_c0,    dim3(1),   dim3(64),  0, stream, C0);
  hipLaunchKernelGGL(transform_k, dim3(ION / 256), dim3(256), 0, stream,
                     k, Ec, Ps, bias, coef, P4, C0);
  hipLaunchKernelGGL(out_init,   dim3(ION / 256), dim3(256), 0, stream, C0, out);
  hipLaunchKernelGGL(ferro_main, dim3(512), dim3(256), 0, stream, x, P4, out);
}

// Round 2
// 83.714 us; speedup vs baseline: 1.0975x; 1.0975x over previous
//
#include <hip/hip_runtime.h>
#include <hip/hip_bf16.h>

// FerroelectricBasis (B=1024, I=64, O=64, N=16)
// out[b,o] = sum_{i,n} [ A*sigmoid(kk*x[b,i] + (br ? E : -E)) + W ]
//   A = 2*Ps*coef, W = (bias-Ps)*coef, kk = -log2e*k, E = log2e*k*Ec
//   br(b,i) = x[b,i] > x[b-1,i]   (row 0 compares vs 0)
//
// 3 kernels, no atomics:
//   prep       : transform params into Q[(i*16+n)*64 + o] = {kk,E,A,W}  (1 MB ws)
//   ferro_main : 16 i-chunks x 64 b-chunks, partials -> ws (4 MB)
//   reduce_k   : sum 16 i-chunk partials -> out

#define LOG2E 1.44269504088896340736f
#define B_DIM 1024
#define I_DIM 64
#define O_DIM 64
#define N_DIM 16
#define ION   65536

__device__ __forceinline__ float ex2(float x) {
#if __has_builtin(__builtin_amdgcn_exp2f)
  return __builtin_amdgcn_exp2f(x);
#else
  return exp2f(x);
#endif
}

__global__ __launch_bounds__(256) void prep(
    const float* __restrict__ k, const float* __restrict__ Ec,
    const float* __restrict__ Ps, const float* __restrict__ bias,
    const float* __restrict__ coef, float4* __restrict__ Q) {
  int idx = blockIdx.x * 256 + threadIdx.x;       // i*1024 + o*16 + n
  int i = idx >> 10, o = (idx >> 4) & 63, n = idx & 15;
  float kv = k[idx], ev = Ec[idx], pv = Ps[idx], bv = bias[idx], cv = coef[idx];
  float kk = -LOG2E * kv;
  float E  =  LOG2E * kv * ev;
  float A  =  2.0f * pv * cv;
  float W  = (bv - pv) * cv;
  Q[(i * N_DIM + n) * O_DIM + o] = make_float4(kk, E, A, W);
}

// grid 1024 = ic(16) x bc(64); block 256 = 4 waves; lane = o (coalesced loads+stores)
// wave w owns rows [bc*16 + w*4, +4), i in [ic*4, +4), all n.
__global__ __launch_bounds__(256) void ferro_main(
    const float* __restrict__ x, const float4* __restrict__ Q,
    float* __restrict__ part) {
  int t  = threadIdx.x;
  int o  = t & 63;
  int w  = t >> 6;
  int ic = blockIdx.x & 15;
  int bc = blockIdx.x >> 4;
  int r0 = bc * 16 + w * 4;

  float acc0 = 0.f, acc1 = 0.f, acc2 = 0.f, acc3 = 0.f, wsum = 0.f;

  #pragma unroll 1
  for (int ii = 0; ii < 4; ++ii) {
    int i = ic * 4 + ii;
    float xm = (r0 == 0) ? 0.0f : x[(r0 - 1) * I_DIM + i];   // wave-uniform broadcast
    float x0 = x[(r0 + 0) * I_DIM + i];
    float x1 = x[(r0 + 1) * I_DIM + i];
    float x2 = x[(r0 + 2) * I_DIM + i];
    float x3 = x[(r0 + 3) * I_DIM + i];
    bool b0 = x0 > xm, b1 = x1 > x0, b2 = x2 > x1, b3 = x3 > x2;

    const float4* q = Q + (i * N_DIM) * O_DIM + o;
    #pragma unroll
    for (int n = 0; n < N_DIM; ++n) {
      float4 p = q[n * O_DIM];                    // coalesced 1KB wave-load
      float E = p.y, nE = -p.y;
      wsum += p.w;
      float e0 = b0 ? E : nE, e1 = b1 ? E : nE, e2 = b2 ? E : nE, e3 = b3 ? E : nE;
      float s0 = __builtin_amdgcn_rcpf(1.0f + ex2(fmaf(p.x, x0, e0)));
      float s1 = __builtin_amdgcn_rcpf(1.0f + ex2(fmaf(p.x, x1, e1)));
      float s2 = __builtin_amdgcn_rcpf(1.0f + ex2(fmaf(p.x, x2, e2)));
      float s3 = __builtin_amdgcn_rcpf(1.0f + ex2(fmaf(p.x, x3, e3)));
      acc0 = fmaf(p.z, s0, acc0);
      acc1 = fmaf(p.z, s1, acc1);
      acc2 = fmaf(p.z, s2, acc2);
      acc3 = fmaf(p.z, s3, acc3);
    }
  }

  float* dst = part + ((size_t)ic * B_DIM + r0) * O_DIM + o;
  dst[0 * O_DIM] = acc0 + wsum;
  dst[1 * O_DIM] = acc1 + wsum;
  dst[2 * O_DIM] = acc2 + wsum;
  dst[3 * O_DIM] = acc3 + wsum;
}

__global__ __launch_bounds__(256) void reduce_k(
    const float* __restrict__ part, float* __restrict__ out) {
  int gid = blockIdx.x * 256 + threadIdx.x;       // b*64 + o
  float s = 0.f;
  #pragma unroll
  for (int ic = 0; ic < 16; ++ic) s += part[ic * (B_DIM * O_DIM) + gid];
  out[gid] = s;
}

extern "C" void kernel_launch(void* const* d_in, const int* in_sizes, int n_in,
                              void* d_out, int out_size, void* d_ws, size_t ws_size,
                              hipStream_t stream) {
  const float* x    = (const float*)d_in[0];
  const float* k    = (const float*)d_in[1];
  const float* Ec   = (const float*)d_in[2];
  const float* Ps   = (const float*)d_in[3];
  const float* bias = (const float*)d_in[4];
  const float* coef = (const float*)d_in[5];
  float* out = (float*)d_out;

  float4* Q    = (float4*)d_ws;                                   // 1 MB
  float*  part = (float*)((char*)d_ws + (size_t)ION * sizeof(float4)); // 4 MB

  hipLaunchKernelGGL(prep,       dim3(ION / 256), dim3(256), 0, stream,
                     k, Ec, Ps, bias, coef, Q);
  hipLaunchKernelGGL(ferro_main, dim3(1024),      dim3(256), 0, stream, x, Q, part);
  hipLaunchKernelGGL(reduce_k,   dim3(B_DIM * O_DIM / 256), dim3(256), 0, stream,
                     part, out);
}

// Round 3
// 83.264 us; speedup vs baseline: 1.1035x; 1.0054x over previous
//
#include <hip/hip_runtime.h>
#include <hip/hip_bf16.h>

// FerroelectricBasis (B=1024, I=64, O=64, N=16)
// out[b,o] = sum_{i,n} [ A*sigmoid_eval + W ]
//   A = 2*Ps*coef, W = (bias-Ps)*coef, kk = -log2e*k, E = log2e*k*Ec
//   sigmoid_eval = 1/(1 + exp2(kk*x[b,i] + (br ? E : -E)))
//   br(b,i) = x[b,i] > x[b-1,i]   (row 0 compares vs 0)
//
// prep   : Q[(i*16+n)*64+o] = {kk,E,A,*}; Wsum[i*64+o] = sum_n W  (no atomics)
// main   : 16 i-chunks x 32 b-chunks, 8 rows/wave, partials -> ws
// reduce : sum 16 i-chunk partials -> out

#define LOG2E 1.44269504088896340736f
#define B_DIM 1024
#define I_DIM 64
#define O_DIM 64
#define N_DIM 16
#define ION   65536

__device__ __forceinline__ float ex2(float x) {
#if __has_builtin(__builtin_amdgcn_exp2f)
  return __builtin_amdgcn_exp2f(x);
#else
  return exp2f(x);
#endif
}

__global__ __launch_bounds__(256) void prep(
    const float* __restrict__ k, const float* __restrict__ Ec,
    const float* __restrict__ Ps, const float* __restrict__ bias,
    const float* __restrict__ coef, float4* __restrict__ Q,
    float* __restrict__ Wsum) {
  int idx = blockIdx.x * 256 + threadIdx.x;       // i*1024 + o*16 + n
  int i = idx >> 10, o = (idx >> 4) & 63, n = idx & 15;
  float kv = k[idx], ev = Ec[idx], pv = Ps[idx], bv = bias[idx], cv = coef[idx];
  float kk = -LOG2E * kv;
  float E  =  LOG2E * kv * ev;
  float A  =  2.0f * pv * cv;
  float W  = (bv - pv) * cv;
  Q[(i * N_DIM + n) * O_DIM + o] = make_float4(kk, E, A, 0.0f);
  // 16 consecutive lanes share (i,o); reduce W over n
  #pragma unroll
  for (int off = 1; off < 16; off <<= 1)
    W += __shfl_xor(W, off, 64);
  if (n == 0) Wsum[i * O_DIM + o] = W;
}

// grid 512 = ic(16) + bc(32)*16; block 256 = 4 waves; lane = o.
// wave w: rows [bc*32 + w*8, +8), i in [ic*4, +4), all n. 8 indep chains/thread.
__global__ __launch_bounds__(256) void ferro_main(
    const float* __restrict__ x, const float4* __restrict__ Q,
    const float* __restrict__ Wsum, float* __restrict__ part) {
  int t  = threadIdx.x;
  int o  = t & 63;
  int w  = t >> 6;
  int ic = blockIdx.x & 15;        // same-ic blocks share XCD (blk%8 = ic%8)
  int bc = blockIdx.x >> 4;        // 0..31
  int r0 = bc * 32 + w * 8;

  float acc[8];
  #pragma unroll
  for (int j = 0; j < 8; ++j) acc[j] = 0.0f;
  float wadd = 0.0f;

  #pragma unroll 1
  for (int ii = 0; ii < 4; ++ii) {
    int i = ic * 4 + ii;
    wadd += Wsum[i * O_DIM + o];
    float xv[9];
    xv[0] = (r0 == 0) ? 0.0f : x[(r0 - 1) * I_DIM + i];
    #pragma unroll
    for (int j = 0; j < 8; ++j) xv[j + 1] = x[(r0 + j) * I_DIM + i];
    bool br[8];
    #pragma unroll
    for (int j = 0; j < 8; ++j) br[j] = xv[j + 1] > xv[j];

    const float4* q = Q + (i * N_DIM) * O_DIM + o;
    #pragma unroll
    for (int n = 0; n < N_DIM; ++n) {
      float4 p = q[n * O_DIM];                    // coalesced 1KB wave-load
      float E = p.y, nE = -p.y;
      #pragma unroll
      for (int j = 0; j < 8; ++j) {
        float e = br[j] ? E : nE;
        float z = fmaf(p.x, xv[j + 1], e);
        float s = __builtin_amdgcn_rcpf(1.0f + ex2(z));
        acc[j] = fmaf(p.z, s, acc[j]);
      }
    }
  }

  float* dst = part + ((size_t)ic * B_DIM + r0) * O_DIM + o;
  #pragma unroll
  for (int j = 0; j < 8; ++j)
    dst[j * O_DIM] = acc[j] + wadd;
}

__global__ __launch_bounds__(256) void reduce_k(
    const float* __restrict__ part, float* __restrict__ out) {
  int gid = blockIdx.x * 256 + threadIdx.x;       // b*64 + o
  float s = 0.f;
  #pragma unroll
  for (int ic = 0; ic < 16; ++ic) s += part[ic * (B_DIM * O_DIM) + gid];
  out[gid] = s;
}

extern "C" void kernel_launch(void* const* d_in, const int* in_sizes, int n_in,
                              void* d_out, int out_size, void* d_ws, size_t ws_size,
                              hipStream_t stream) {
  const float* x    = (const float*)d_in[0];
  const float* k    = (const float*)d_in[1];
  const float* Ec   = (const float*)d_in[2];
  const float* Ps   = (const float*)d_in[3];
  const float* bias = (const float*)d_in[4];
  const float* coef = (const float*)d_in[5];
  float* out = (float*)d_out;

  float4* Q    = (float4*)d_ws;                                        // 1 MB
  float*  Wsum = (float*)((char*)d_ws + (size_t)ION * sizeof(float4)); // 16 KB
  float*  part = (float*)((char*)Wsum + (size_t)I_DIM * O_DIM * sizeof(float)); // 4 MB

  hipLaunchKernelGGL(prep,       dim3(ION / 256), dim3(256), 0, stream,
                     k, Ec, Ps, bias, coef, Q, Wsum);
  hipLaunchKernelGGL(ferro_main, dim3(512),       dim3(256), 0, stream,
                     x, Q, Wsum, part);
  hipLaunchKernelGGL(reduce_k,   dim3(B_DIM * O_DIM / 256), dim3(256), 0, stream,
                     part, out);
}